// Round 7
// baseline (154.072 us; speedup 1.0000x reference)
//
#include <hip/hip_runtime.h>
#include <hip/hip_bf16.h>

// B=8, T=2048, C=1024, H=64 single-head causal attention. f32 in, f32 out.
// Round 16: qkv intra-block double-buffer. Round-15 qkv serialized its two
// phases (stage 256 KB/CU ~11us chip-wide, then LDS-bound compute ~8us) at
// 1 block/CU. Split by ROW HALF: row-groups 0-1 read LDS half0 only, rg 2-3
// half1 only. Schedule: stage half0 -> barrier -> issue half1 HBM loads to
// regs (sched_barrier pins issue) -> pass A (rg0-1, loads fly underneath) ->
// write half1 LDS -> barrier -> pass B (rg2-3). The wf ring's wrap refills
// at kci=30/31 are exactly pass B's first fragments -> Wt read ONCE
// (384 KB/CU, round-5 lesson preserved). attn/transpose_w unchanged.
// fillBufferAligned (268 MB ws-poison, ~41us) is unconditional harness
// overhead — fixed floor, confirmed present even when d_ws is unused (R3).
// Region map: region rt (0..1023) = 16 tokens, stride regsz bf16.
// Q[t][h]@0, K[t][h]@1024, V^T[h][t16]@2048 inside each region.

typedef __bf16 bf16;
typedef __bf16 bf16x8 __attribute__((ext_vector_type(8)));
typedef float f32x4 __attribute__((ext_vector_type(4)));
typedef unsigned int u32;
typedef u32 u32x2 __attribute__((ext_vector_type(2)));
typedef u32 u32x4 __attribute__((ext_vector_type(4)));

#define T_SZ 2048
#define C_SZ 1024
#define H_SZ 64
#define QOFF 0
#define KOFF 1024
#define VOFF 2048
#define PPITCH 72
#define NEG_BIG (-30000.0f)
#define QSCALE 0.04508422f  // (1/32) * log2(e)

__device__ __forceinline__ bf16x8 ld8(const bf16* p) { return *(const bf16x8*)p; }

// DPP rotate within 16-lane row. ROW_ROR:n = 0x120|n.
template <int CTRL>
__device__ __forceinline__ float dpp_mov(float x) {
  return __builtin_bit_cast(float,
      __builtin_amdgcn_update_dpp(0, __builtin_bit_cast(int, x), CTRL, 0xf, 0xf, true));
}
__device__ __forceinline__ float qmax16(float x) {
  x = fmaxf(x, dpp_mov<0x121>(x));
  x = fmaxf(x, dpp_mov<0x122>(x));
  x = fmaxf(x, dpp_mov<0x124>(x));
  x = fmaxf(x, dpp_mov<0x128>(x));
  return x;
}
__device__ __forceinline__ float qsum16(float x) {
  x += dpp_mov<0x121>(x);
  x += dpp_mov<0x122>(x);
  x += dpp_mov<0x124>(x);
  x += dpp_mov<0x128>(x);
  return x;
}

// ---------------------------------------------------------------------------
// Wt[mat][h][c] = W[mat][c][h] (bf16); QSCALE folded into Wq.
__global__ __launch_bounds__(256) void transpose_w(const float* __restrict__ Wq,
                                                   const float* __restrict__ Wk,
                                                   const float* __restrict__ Wv,
                                                   bf16* __restrict__ Wt) {
  __shared__ float sh[64][65];
  int ct = blockIdx.x;
  int mat = blockIdx.y;
  const float* W = (mat == 0) ? Wq : (mat == 1 ? Wk : Wv);
  int tid = threadIdx.x;
  int r = tid >> 2, cb = (tid & 3) * 16;

  const f32x4* src = (const f32x4*)(W + (size_t)(ct * 64 + r) * H_SZ + cb);
#pragma unroll
  for (int v = 0; v < 4; ++v) {
    f32x4 x = src[v];
#pragma unroll
    for (int j = 0; j < 4; ++j) sh[r][cb + v * 4 + j] = x[j];
  }
  __syncthreads();

  float scale = (mat == 0) ? QSCALE : 1.0f;
  bf16x8 o0, o1;
#pragma unroll
  for (int j = 0; j < 8; ++j) o0[j] = (bf16)(sh[cb + j][r] * scale);
#pragma unroll
  for (int j = 0; j < 8; ++j) o1[j] = (bf16)(sh[cb + 8 + j][r] * scale);
  bf16* dst = Wt + ((size_t)mat * H_SZ + r) * C_SZ + ct * 64 + cb;
  *(bf16x8*)dst = o0;
  *(bf16x8*)(dst + 8) = o1;
}

// ---------------------------------------------------------------------------
// QKV: 256 blocks x 768 thr (12 waves), 1 block/CU, M=64 tokens.
// Wave j owns ONE 16-col Wt fragment (j<4 Q, j<8 K, else V), feeding 2 MFMAs
// per pass per kci (row-groups). Per-CU Wt traffic = 384 KB (read once; the
// ring carries across the passes). LDS: 64 rows x 2048 B = 128 KiB, byte XOR
// swizzle (bo ^= (row&7)<<4) on write+read (stride-2048 conflict fix).
// Intra-block double buffer: half0 = rows 0..31 (rg 0,1), half1 = rows
// 32..63 (rg 2,3); half1's HBM loads are in flight during pass A.
//   Q/K: mfma(wf, df) -> D[h][t];  V: mfma(df, wf) -> D[t][h].
// -> every epilogue store is a packed 8B store.
__global__ __launch_bounds__(768, 3) void qkv(const float* data, const bf16* __restrict__ Wt,
                                              bf16* arena, int regsz) {
  __shared__ bf16 As[64 * 1024];  // 128 KiB, swizzled addressing via bytes
  char* As_b = (char*)As;
  int blk = blockIdx.x;
  int tid = threadIdx.x;
  int w = tid >> 6, lane = tid & 63;
  int l15 = lane & 15, quad = lane >> 4;

  const float* src = data + (size_t)blk * 64 * C_SZ;

  // ---- stage half 0: rows 0..31 (8192 f32x4 units over 768 threads) ------
  {
    f32x4 st[11];
#pragma unroll
    for (int i = 0; i < 11; ++i) {
      if (i < 10 || tid < 512) {
        int u = i * 768 + tid;
        st[i] = __builtin_nontemporal_load(
            (const f32x4*)(src + (size_t)(u >> 8) * C_SZ + (u & 255) * 4));
      }
    }
#pragma unroll
    for (int i = 0; i < 11; ++i) {
      if (i < 10 || tid < 512) {
        int u = i * 768 + tid;
        int row = u >> 8, c4 = u & 255;
        bf16 t4[4] = {(bf16)st[i][0], (bf16)st[i][1], (bf16)st[i][2], (bf16)st[i][3]};
        int bo = (row * 2048 + c4 * 8) ^ ((row & 7) << 4);
        *(u32x2*)(As_b + bo) = *(const u32x2*)t4;
      }
    }
  }
  __syncthreads();  // half0 visible

  // ---- issue half 1 loads (rows 32..63) into registers --------------------
  f32x4 st2[11];
#pragma unroll
  for (int i = 0; i < 11; ++i) {
    if (i < 10 || tid < 512) {
      int u = 8192 + i * 768 + tid;
      st2[i] = __builtin_nontemporal_load(
          (const f32x4*)(src + (size_t)(u >> 8) * C_SZ + (u & 255) * 4));
    }
  }
  __builtin_amdgcn_sched_barrier(0);  // pin load issue before pass A

  // ---- compute setup: wave w owns fragment-col j = w ----------------------
  int j = w;
  const bf16* wb = Wt + (size_t)(j * 16 + l15) * C_SZ + quad * 8;
  bf16x8 wf[2];
  wf[0] = ld8(wb);       // kci 0
  wf[1] = ld8(wb + 32);  // kci 1

  f32x4 acc[4];
  f32x4 zero = {0.f, 0.f, 0.f, 0.f};
#pragma unroll
  for (int rg = 0; rg < 4; ++rg) acc[rg] = zero;

  bool isQK = (j < 8);
  int swz = (l15 & 7) << 4;  // row&7 of (rg*16+l15) == l15&7

  // ---- pass A: row-groups 0,1 (rows 0..31), half1 loads in flight ---------
#pragma unroll 2
  for (int kci = 0; kci < 32; ++kci) {
    int cur = kci & 1;  // compile-time under unroll 2
    bf16x8 df[2];
#pragma unroll
    for (int rg = 0; rg < 2; ++rg) {
      int bo = ((rg * 16 + l15) * 2048 + kci * 64 + quad * 16) ^ swz;
      df[rg] = ld8((const bf16*)(As_b + bo));
    }
    if (isQK) {
      acc[0] = __builtin_amdgcn_mfma_f32_16x16x32_bf16(wf[cur], df[0], acc[0], 0, 0, 0);
      acc[1] = __builtin_amdgcn_mfma_f32_16x16x32_bf16(wf[cur], df[1], acc[1], 0, 0, 0);
    } else {
      acc[0] = __builtin_amdgcn_mfma_f32_16x16x32_bf16(df[0], wf[cur], acc[0], 0, 0, 0);
      acc[1] = __builtin_amdgcn_mfma_f32_16x16x32_bf16(df[1], wf[cur], acc[1], 0, 0, 0);
    }
    // wrap refill: at kci=30/31 this reloads fragments kci 0/1 — which is
    // exactly the ring state pass B starts from (Wt read once total).
    wf[cur] = ld8(wb + ((kci + 2) & 31) * 32);
  }

  // ---- write half 1 to LDS (rows 32..63; disjoint from pass-A reads) ------
#pragma unroll
  for (int i = 0; i < 11; ++i) {
    if (i < 10 || tid < 512) {
      int u = 8192 + i * 768 + tid;
      int row = u >> 8, c4 = u & 255;
      bf16 t4[4] = {(bf16)st2[i][0], (bf16)st2[i][1], (bf16)st2[i][2], (bf16)st2[i][3]};
      int bo = (row * 2048 + c4 * 8) ^ ((row & 7) << 4);
      *(u32x2*)(As_b + bo) = *(const u32x2*)t4;
    }
  }
  __syncthreads();  // half1 visible

  // ---- pass B: row-groups 2,3 (rows 32..63), wf ring continues ------------
#pragma unroll 2
  for (int kci = 0; kci < 32; ++kci) {
    int cur = kci & 1;
    bf16x8 df[2];
#pragma unroll
    for (int rg = 0; rg < 2; ++rg) {
      int bo = (((rg + 2) * 16 + l15) * 2048 + kci * 64 + quad * 16) ^ swz;
      df[rg] = ld8((const bf16*)(As_b + bo));
    }
    if (isQK) {
      acc[2] = __builtin_amdgcn_mfma_f32_16x16x32_bf16(wf[cur], df[0], acc[2], 0, 0, 0);
      acc[3] = __builtin_amdgcn_mfma_f32_16x16x32_bf16(wf[cur], df[1], acc[3], 0, 0, 0);
    } else {
      acc[2] = __builtin_amdgcn_mfma_f32_16x16x32_bf16(df[0], wf[cur], acc[2], 0, 0, 0);
      acc[3] = __builtin_amdgcn_mfma_f32_16x16x32_bf16(df[1], wf[cur], acc[3], 0, 0, 0);
    }
    wf[cur] = ld8(wb + ((kci + 2) & 31) * 32);
  }

  // ---- epilogue: packed 8B stores into 4 sub-regions ----------------------
#pragma unroll
  for (int rg = 0; rg < 4; ++rg) {
    bf16* reg = arena + (size_t)(blk * 4 + rg) * (size_t)regsz;
    bf16 p4[4] = {(bf16)acc[rg][0], (bf16)acc[rg][1], (bf16)acc[rg][2], (bf16)acc[rg][3]};
    if (j < 4) {         // Q: D[h][t], t=l15, h = j*16 + quad*4 + r
      bf16* dst = reg + QOFF + l15 * 64 + j * 16 + quad * 4;
      *(u32x2*)dst = *(const u32x2*)p4;
    } else if (j < 8) {  // K
      bf16* dst = reg + KOFF + l15 * 64 + (j - 4) * 16 + quad * 4;
      *(u32x2*)dst = *(const u32x2*)p4;
    } else {             // V: D[t][h] -> V^T[h][t16], h = (j-8)*16 + l15
      bf16* dst = reg + VOFF + ((j - 8) * 16 + l15) * 16 + quad * 4;
      *(u32x2*)dst = *(const u32x2*)p4;
    }
  }
}

// ---------------------------------------------------------------------------
// Flash attention. Block = one (qt, slice, b) 16x64 output tile; 4 waves each
// own a QUARTER of kt in [0, qt], private (m,l,accO); one LDS merge at end.
// Grid 1024 1-D: b = id&7 (pins batch b to XCD b under round-robin dispatch:
// that XCD's L2 then holds one batch's K/V/Q). t = id>>3, slice = t&3,
// qt = 31-(t>>2) (LPT order). 4 blocks/CU -> 16 waves/CU.
// No K prefetch, V in two 16-reg halves -> fits (256,4) 128-reg budget with
// no scratch; latency hiding via 4 waves/SIMD TLP.
__global__ __launch_bounds__(256, 4) void attn(const bf16* __restrict__ arena,
                                               float* __restrict__ out, int regsz) {
  __shared__ bf16 Ps[4][16 * PPITCH];
  __shared__ f32x4 Mg[3][6][64];  // waves 1..3 dump {accO[0..3], m, l}
  int id = blockIdx.x;
  int b = id & 7;
  int t = id >> 3;
  int slice = t & 3;
  int qt = 31 - (t >> 2);
  int tid = threadIdx.x;
  int w = tid >> 6, lane = tid & 63;
  int l15 = lane & 15, quad = lane >> 4;

  const bf16* base = arena + (size_t)b * 128 * (size_t)regsz;

  const bf16* qreg = base + (size_t)(qt * 4 + slice) * (size_t)regsz + QOFF + l15 * 64;
  bf16x8 qf0 = ld8(qreg + quad * 8);
  bf16x8 qf1 = ld8(qreg + 32 + quad * 8);

  f32x4 accO[4];
  f32x4 zero = {0.f, 0.f, 0.f, 0.f};
#pragma unroll
  for (int nt = 0; nt < 4; ++nt) accO[nt] = zero;
  float m[4], l[4];
#pragma unroll
  for (int r = 0; r < 4; ++r) { m[r] = NEG_BIG; l[r] = 0.f; }

  int qrow_base = qt * 64 + slice * 16 + quad * 4;
  int vro = (quad >> 1);                 // V region sub-index
  int vco = (quad & 1) * 8;              // V in-row offset

  // this wave's kt quarter
  int q4 = (qt + 4) >> 2;                // ceil((qt+1)/4)
  int kbeg = w * q4;
  int kend = min((w + 1) * q4, qt + 1);  // may be empty (kbeg >= kend)

  for (int kt = kbeg; kt < kend; ++kt) {
    // K fragments for this tile (L2-resident; TLP hides latency)
    bf16x8 kf[8];
#pragma unroll
    for (int nt = 0; nt < 4; ++nt) {
      const bf16* kp = base + (size_t)(kt * 4 + nt) * (size_t)regsz + KOFF + l15 * 64 + quad * 8;
      kf[2 * nt] = ld8(kp);
      kf[2 * nt + 1] = ld8(kp + 32);
    }

    f32x4 sA[4];
#pragma unroll
    for (int nt = 0; nt < 4; ++nt) sA[nt] = zero;
#pragma unroll
    for (int nt = 0; nt < 4; ++nt) {
      sA[nt] = __builtin_amdgcn_mfma_f32_16x16x32_bf16(qf0, kf[2 * nt], sA[nt], 0, 0, 0);
      sA[nt] = __builtin_amdgcn_mfma_f32_16x16x32_bf16(qf1, kf[2 * nt + 1], sA[nt], 0, 0, 0);
    }

    // first V half: issue under the softmax (kf regs die at the MFMAs above)
    bf16x8 vf0[4];
#pragma unroll
    for (int nt = 0; nt < 4; ++nt) {
      const bf16* vp = base + (size_t)(kt * 4 + vro) * (size_t)regsz + VOFF +
                       (nt * 16 + l15) * 16 + vco;
      vf0[nt] = ld8(vp);
    }

    if (kt == qt) {  // causal mask on diagonal tile
#pragma unroll
      for (int nt = 0; nt < 4; ++nt) {
        int colg = kt * 64 + nt * 16 + l15;
#pragma unroll
        for (int r = 0; r < 4; ++r)
          if (colg > qrow_base + r) sA[nt][r] = NEG_BIG;
      }
    }

    float alpha[4];
#pragma unroll
    for (int r = 0; r < 4; ++r) {
      float mx = qmax16(fmaxf(fmaxf(sA[0][r], sA[1][r]), fmaxf(sA[2][r], sA[3][r])));
      float mnew = fmaxf(m[r], mx);
      alpha[r] = exp2f(m[r] - mnew);
      m[r] = mnew;
    }

    float rs[4] = {0.f, 0.f, 0.f, 0.f};
#pragma unroll
    for (int nt = 0; nt < 4; ++nt) {
#pragma unroll
      for (int r = 0; r < 4; ++r) {
        float p = exp2f(sA[nt][r] - m[r]);
        sA[nt][r] = p;
        rs[r] += p;
      }
    }
#pragma unroll
    for (int r = 0; r < 4; ++r) l[r] = l[r] * alpha[r] + qsum16(rs[r]);

    // P: C/D layout -> per-wave LDS -> A layout (same-wave RAW, lgkm-ordered)
#pragma unroll
    for (int nt = 0; nt < 4; ++nt) {
#pragma unroll
      for (int r = 0; r < 4; ++r)
        Ps[w][(quad * 4 + r) * PPITCH + nt * 16 + l15] = (bf16)sA[nt][r];
    }

    // second V half: issue before PV so latency hides under first PV block
    bf16x8 vf1[4];
#pragma unroll
    for (int nt = 0; nt < 4; ++nt) {
      const bf16* vp = base + (size_t)(kt * 4 + 2 + vro) * (size_t)regsz + VOFF +
                       (nt * 16 + l15) * 16 + vco;
      vf1[nt] = ld8(vp);
    }

#pragma unroll
    for (int nt = 0; nt < 4; ++nt) {
#pragma unroll
      for (int r = 0; r < 4; ++r) accO[nt][r] *= alpha[r];
    }
    bf16x8 pf0 = ld8((const bf16*)Ps[w] + l15 * PPITCH + quad * 8);
    bf16x8 pf1 = ld8((const bf16*)Ps[w] + l15 * PPITCH + 32 + quad * 8);
#pragma unroll
    for (int nt = 0; nt < 4; ++nt)
      accO[nt] = __builtin_amdgcn_mfma_f32_16x16x32_bf16(pf0, vf0[nt], accO[nt], 0, 0, 0);
#pragma unroll
    for (int nt = 0; nt < 4; ++nt)
      accO[nt] = __builtin_amdgcn_mfma_f32_16x16x32_bf16(pf1, vf1[nt], accO[nt], 0, 0, 0);
  }

  // merge the 4 kt-quarter partials (exact: O* = sum_w O_w * 2^(m_w - m*))
  if (w > 0) {
#pragma unroll
    for (int nt = 0; nt < 4; ++nt) Mg[w - 1][nt][lane] = accO[nt];
    f32x4 mv = {m[0], m[1], m[2], m[3]};
    f32x4 lv = {l[0], l[1], l[2], l[3]};
    Mg[w - 1][4][lane] = mv;
    Mg[w - 1][5][lane] = lv;
  }
  __syncthreads();
  if (w == 0) {
#pragma unroll
    for (int wv = 0; wv < 3; ++wv) {
      f32x4 mo = Mg[wv][4][lane];
      f32x4 lo = Mg[wv][5][lane];
      f32x4 oo[4];
#pragma unroll
      for (int nt = 0; nt < 4; ++nt) oo[nt] = Mg[wv][nt][lane];
#pragma unroll
      for (int r = 0; r < 4; ++r) {
        float mnew = fmaxf(m[r], mo[r]);
        float a = exp2f(m[r] - mnew);
        float bs = exp2f(mo[r] - mnew);
        l[r] = l[r] * a + lo[r] * bs;
#pragma unroll
        for (int nt = 0; nt < 4; ++nt) accO[nt][r] = accO[nt][r] * a + oo[nt][r] * bs;
        m[r] = mnew;
      }
    }

    float inv[4];
#pragma unroll
    for (int r = 0; r < 4; ++r) inv[r] = 1.f / l[r];
#pragma unroll
    for (int nt = 0; nt < 4; ++nt) {
#pragma unroll
      for (int r = 0; r < 4; ++r) {
        int tk = qt * 64 + slice * 16 + quad * 4 + r;
        int h = nt * 16 + l15;
        out[((size_t)b * T_SZ + tk) * H_SZ + h] = accO[nt][r] * inv[r];
      }
    }
  }
}

// ---------------------------------------------------------------------------
extern "C" void kernel_launch(void* const* d_in, const int* in_sizes, int n_in,
                              void* d_out, int out_size, void* d_ws, size_t ws_size,
                              hipStream_t stream) {
  const float* data = (const float*)d_in[0];

  // Preferred: arena (1024 regions x 4096 bf16 = 8 MB) + Wt (384 KB) in d_ws.
  // Fallback (tiny ws): alias input (stride 32768) + Wt in d_out. Each M=64
  // qkv block fully consumes its own 256 KB input (half0 via LDS, half1 via
  // registers) before its epilogue writes it.
  const size_t arena_bytes = (size_t)1024 * 4096 * sizeof(bf16);  // 8 MB
  const size_t wt_bytes = (size_t)3 * H_SZ * C_SZ * sizeof(bf16); // 384 KB
  bool ws_ok = (d_ws != nullptr) && (ws_size >= arena_bytes + wt_bytes);

  bf16* arena = ws_ok ? (bf16*)d_ws : (bf16*)d_in[0];
  bf16* Wt = ws_ok ? (bf16*)((char*)d_ws + arena_bytes) : (bf16*)d_out;
  int regsz = ws_ok ? 4096 : 32768;

  transpose_w<<<dim3(16, 3), 256, 0, stream>>>((const float*)d_in[1],
                                               (const float*)d_in[2],
                                               (const float*)d_in[3], Wt);
  qkv<<<256, 768, 0, stream>>>(data, Wt, arena, regsz);
  attn<<<1024, 256, 0, stream>>>(arena, (float*)d_out, regsz);
}

// Round 8
// 143.205 us; speedup vs baseline: 1.0759x; 1.0759x over previous
//
#include <hip/hip_runtime.h>
#include <hip/hip_bf16.h>

// B=8, T=2048, C=1024, H=64 single-head causal attention. f32 in, f32 out.
// Round 17: revert R7's double-buffer (it silently doubled Wt traffic to
// 768 KB/CU -> regression, confirming the Wt-bytes/CU scaling law) back to
// the R15/R6 single-pass 12-wave structure, and replace the XOR-swizzled
// LDS with a TILED layout As[kci][row][quad] (bo = kci*4096 + row*64 +
// quad*16): a wave's df read now covers 1024 consecutive bytes -> provably
// bank-conflict-free, no swizzle-phasing assumptions. Staging writes become
// 8-way on 8B stores but are only ~252 wave-instrs/CU (~1 us) — cheap side
// of the trade. Wt read once per CU (384 KB). attn/transpose_w unchanged.
// fillBufferAligned (268 MB ws-poison, ~41 us) is unconditional harness
// overhead — fixed floor (present even when d_ws is unused, R3).
// Region map: region rt (0..1023) = 16 tokens, stride regsz bf16.
// Q[t][h]@0, K[t][h]@1024, V^T[h][t16]@2048 inside each region.

typedef __bf16 bf16;
typedef __bf16 bf16x8 __attribute__((ext_vector_type(8)));
typedef float f32x4 __attribute__((ext_vector_type(4)));
typedef unsigned int u32;
typedef u32 u32x2 __attribute__((ext_vector_type(2)));
typedef u32 u32x4 __attribute__((ext_vector_type(4)));

#define T_SZ 2048
#define C_SZ 1024
#define H_SZ 64
#define QOFF 0
#define KOFF 1024
#define VOFF 2048
#define PPITCH 72
#define NEG_BIG (-30000.0f)
#define QSCALE 0.04508422f  // (1/32) * log2(e)

__device__ __forceinline__ bf16x8 ld8(const bf16* p) { return *(const bf16x8*)p; }

// DPP rotate within 16-lane row. ROW_ROR:n = 0x120|n.
template <int CTRL>
__device__ __forceinline__ float dpp_mov(float x) {
  return __builtin_bit_cast(float,
      __builtin_amdgcn_update_dpp(0, __builtin_bit_cast(int, x), CTRL, 0xf, 0xf, true));
}
__device__ __forceinline__ float qmax16(float x) {
  x = fmaxf(x, dpp_mov<0x121>(x));
  x = fmaxf(x, dpp_mov<0x122>(x));
  x = fmaxf(x, dpp_mov<0x124>(x));
  x = fmaxf(x, dpp_mov<0x128>(x));
  return x;
}
__device__ __forceinline__ float qsum16(float x) {
  x += dpp_mov<0x121>(x);
  x += dpp_mov<0x122>(x);
  x += dpp_mov<0x124>(x);
  x += dpp_mov<0x128>(x);
  return x;
}

// ---------------------------------------------------------------------------
// Wt[mat][h][c] = W[mat][c][h] (bf16); QSCALE folded into Wq.
__global__ __launch_bounds__(256) void transpose_w(const float* __restrict__ Wq,
                                                   const float* __restrict__ Wk,
                                                   const float* __restrict__ Wv,
                                                   bf16* __restrict__ Wt) {
  __shared__ float sh[64][65];
  int ct = blockIdx.x;
  int mat = blockIdx.y;
  const float* W = (mat == 0) ? Wq : (mat == 1 ? Wk : Wv);
  int tid = threadIdx.x;
  int r = tid >> 2, cb = (tid & 3) * 16;

  const f32x4* src = (const f32x4*)(W + (size_t)(ct * 64 + r) * H_SZ + cb);
#pragma unroll
  for (int v = 0; v < 4; ++v) {
    f32x4 x = src[v];
#pragma unroll
    for (int j = 0; j < 4; ++j) sh[r][cb + v * 4 + j] = x[j];
  }
  __syncthreads();

  float scale = (mat == 0) ? QSCALE : 1.0f;
  bf16x8 o0, o1;
#pragma unroll
  for (int j = 0; j < 8; ++j) o0[j] = (bf16)(sh[cb + j][r] * scale);
#pragma unroll
  for (int j = 0; j < 8; ++j) o1[j] = (bf16)(sh[cb + 8 + j][r] * scale);
  bf16* dst = Wt + ((size_t)mat * H_SZ + r) * C_SZ + ct * 64 + cb;
  *(bf16x8*)dst = o0;
  *(bf16x8*)(dst + 8) = o1;
}

// ---------------------------------------------------------------------------
// QKV: 256 blocks x 768 thr (12 waves), 1 block/CU, M=64 tokens.
// Wave j (0..11) owns ONE 16-col Wt fragment (j<4 Q, j<8 K, else V) and
// feeds it to 4 MFMAs (row-groups rg=0..3) per kci. Per-CU Wt traffic =
// 384 KB (each fragment-col read once per kci per block; depth-2 ring).
// LDS: tiled As[kci][row][quad], bo = kci*4096 + row*64 + quad*16 (128 KiB).
// A wave's df read = 1024 CONSECUTIVE bytes (l15*64+quad*16 tiles 0..1023)
// -> conflict-free by construction. Staging writes (8B each) are 8-way but
// only ~252 wave-instrs/CU -> ~1 us, the cheap side of the trade.
//   Q/K: mfma(wf, df) -> D[h][t];  V: mfma(df, wf) -> D[t][h].
// -> every epilogue store is a packed 8B store.
__global__ __launch_bounds__(768, 3) void qkv(const float* data, const bf16* __restrict__ Wt,
                                              bf16* arena, int regsz) {
  __shared__ bf16 As[64 * 1024];  // 128 KiB, tiled addressing via bytes
  char* As_b = (char*)As;
  int blk = blockIdx.x;
  int tid = threadIdx.x;
  int w = tid >> 6, lane = tid & 63;
  int l15 = lane & 15, quad = lane >> 4;

  // ---- stage 64 rows x 1024 f32 -> bf16 LDS (nontemporal, full coverage) --
  const float* src = data + (size_t)blk * 64 * C_SZ;
#pragma unroll
  for (int g = 0; g < 3; ++g) {
    f32x4 st[7];
#pragma unroll
    for (int i = 0; i < 7; ++i) {
      int u = (g * 7 + i) * 768 + tid;  // u < 16128 = rows 0..62
      st[i] = __builtin_nontemporal_load(
          (const f32x4*)(src + (size_t)(u >> 8) * C_SZ + (u & 255) * 4));
    }
#pragma unroll
    for (int i = 0; i < 7; ++i) {
      int u = (g * 7 + i) * 768 + tid;
      int row = u >> 8, c4 = u & 255;
      bf16 t4[4] = {(bf16)st[i][0], (bf16)st[i][1], (bf16)st[i][2], (bf16)st[i][3]};
      int bo = ((c4 >> 3) << 12) + row * 64 + (c4 & 7) * 8;
      *(u32x2*)(As_b + bo) = *(const u32x2*)t4;
    }
  }
  if (tid < 256) {  // tail: row 63
    int c4 = tid;
    f32x4 x = __builtin_nontemporal_load(
        (const f32x4*)(src + (size_t)63 * C_SZ + c4 * 4));
    bf16 t4[4] = {(bf16)x[0], (bf16)x[1], (bf16)x[2], (bf16)x[3]};
    int bo = ((c4 >> 3) << 12) + 63 * 64 + (c4 & 7) * 8;
    *(u32x2*)(As_b + bo) = *(const u32x2*)t4;
  }
  __syncthreads();

  // ---- compute: wave w owns fragment-col j = w ---------------------------
  int j = w;
  const bf16* wb = Wt + (size_t)(j * 16 + l15) * C_SZ + quad * 8;
  bf16x8 wf[2];
  wf[0] = ld8(wb);       // kci 0
  wf[1] = ld8(wb + 32);  // kci 1

  f32x4 acc[4];
  f32x4 zero = {0.f, 0.f, 0.f, 0.f};
#pragma unroll
  for (int rg = 0; rg < 4; ++rg) acc[rg] = zero;

  bool isQK = (j < 8);
  int lbase = l15 * 64 + quad * 16;  // lane offset within a 1024B (kci,rg) slab

#pragma unroll 2
  for (int kci = 0; kci < 32; ++kci) {
    int cur = kci & 1;  // compile-time under unroll 2
    bf16x8 df[4];
#pragma unroll
    for (int rg = 0; rg < 4; ++rg) {
      int bo = (kci << 12) + rg * 1024 + lbase;
      df[rg] = ld8((const bf16*)(As_b + bo));
    }
    if (isQK) {
#pragma unroll
      for (int rg = 0; rg < 4; ++rg)
        acc[rg] = __builtin_amdgcn_mfma_f32_16x16x32_bf16(wf[cur], df[rg], acc[rg], 0, 0, 0);
    } else {
#pragma unroll
      for (int rg = 0; rg < 4; ++rg)
        acc[rg] = __builtin_amdgcn_mfma_f32_16x16x32_bf16(df[rg], wf[cur], acc[rg], 0, 0, 0);
    }
    wf[cur] = ld8(wb + ((kci + 2) & 31) * 32);  // refill for kci+2 (wrap-safe)
  }

  // ---- epilogue: packed 8B stores into 4 sub-regions ---------------------
#pragma unroll
  for (int rg = 0; rg < 4; ++rg) {
    bf16* reg = arena + (size_t)(blk * 4 + rg) * (size_t)regsz;
    bf16 p4[4] = {(bf16)acc[rg][0], (bf16)acc[rg][1], (bf16)acc[rg][2], (bf16)acc[rg][3]};
    if (j < 4) {         // Q: D[h][t], t=l15, h = j*16 + quad*4 + r
      bf16* dst = reg + QOFF + l15 * 64 + j * 16 + quad * 4;
      *(u32x2*)dst = *(const u32x2*)p4;
    } else if (j < 8) {  // K
      bf16* dst = reg + KOFF + l15 * 64 + (j - 4) * 16 + quad * 4;
      *(u32x2*)dst = *(const u32x2*)p4;
    } else {             // V: D[t][h] -> V^T[h][t16], h = (j-8)*16 + l15
      bf16* dst = reg + VOFF + ((j - 8) * 16 + l15) * 16 + quad * 4;
      *(u32x2*)dst = *(const u32x2*)p4;
    }
  }
}

// ---------------------------------------------------------------------------
// Flash attention. Block = one (qt, slice, b) 16x64 output tile; 4 waves each
// own a QUARTER of kt in [0, qt], private (m,l,accO); one LDS merge at end.
// Grid 1024 1-D: b = id&7 (pins batch b to XCD b under round-robin dispatch:
// that XCD's L2 then holds one batch's K/V/Q). t = id>>3, slice = t&3,
// qt = 31-(t>>2) (LPT order). 4 blocks/CU -> 16 waves/CU.
// No K prefetch, V in two 16-reg halves -> fits (256,4) 128-reg budget with
// no scratch; latency hiding via 4 waves/SIMD TLP.
__global__ __launch_bounds__(256, 4) void attn(const bf16* __restrict__ arena,
                                               float* __restrict__ out, int regsz) {
  __shared__ bf16 Ps[4][16 * PPITCH];
  __shared__ f32x4 Mg[3][6][64];  // waves 1..3 dump {accO[0..3], m, l}
  int id = blockIdx.x;
  int b = id & 7;
  int t = id >> 3;
  int slice = t & 3;
  int qt = 31 - (t >> 2);
  int tid = threadIdx.x;
  int w = tid >> 6, lane = tid & 63;
  int l15 = lane & 15, quad = lane >> 4;

  const bf16* base = arena + (size_t)b * 128 * (size_t)regsz;

  const bf16* qreg = base + (size_t)(qt * 4 + slice) * (size_t)regsz + QOFF + l15 * 64;
  bf16x8 qf0 = ld8(qreg + quad * 8);
  bf16x8 qf1 = ld8(qreg + 32 + quad * 8);

  f32x4 accO[4];
  f32x4 zero = {0.f, 0.f, 0.f, 0.f};
#pragma unroll
  for (int nt = 0; nt < 4; ++nt) accO[nt] = zero;
  float m[4], l[4];
#pragma unroll
  for (int r = 0; r < 4; ++r) { m[r] = NEG_BIG; l[r] = 0.f; }

  int qrow_base = qt * 64 + slice * 16 + quad * 4;
  int vro = (quad >> 1);                 // V region sub-index
  int vco = (quad & 1) * 8;              // V in-row offset

  // this wave's kt quarter
  int q4 = (qt + 4) >> 2;                // ceil((qt+1)/4)
  int kbeg = w * q4;
  int kend = min((w + 1) * q4, qt + 1);  // may be empty (kbeg >= kend)

  for (int kt = kbeg; kt < kend; ++kt) {
    // K fragments for this tile (L2-resident; TLP hides latency)
    bf16x8 kf[8];
#pragma unroll
    for (int nt = 0; nt < 4; ++nt) {
      const bf16* kp = base + (size_t)(kt * 4 + nt) * (size_t)regsz + KOFF + l15 * 64 + quad * 8;
      kf[2 * nt] = ld8(kp);
      kf[2 * nt + 1] = ld8(kp + 32);
    }

    f32x4 sA[4];
#pragma unroll
    for (int nt = 0; nt < 4; ++nt) sA[nt] = zero;
#pragma unroll
    for (int nt = 0; nt < 4; ++nt) {
      sA[nt] = __builtin_amdgcn_mfma_f32_16x16x32_bf16(qf0, kf[2 * nt], sA[nt], 0, 0, 0);
      sA[nt] = __builtin_amdgcn_mfma_f32_16x16x32_bf16(qf1, kf[2 * nt + 1], sA[nt], 0, 0, 0);
    }

    // first V half: issue under the softmax (kf regs die at the MFMAs above)
    bf16x8 vf0[4];
#pragma unroll
    for (int nt = 0; nt < 4; ++nt) {
      const bf16* vp = base + (size_t)(kt * 4 + vro) * (size_t)regsz + VOFF +
                       (nt * 16 + l15) * 16 + vco;
      vf0[nt] = ld8(vp);
    }

    if (kt == qt) {  // causal mask on diagonal tile
#pragma unroll
      for (int nt = 0; nt < 4; ++nt) {
        int colg = kt * 64 + nt * 16 + l15;
#pragma unroll
        for (int r = 0; r < 4; ++r)
          if (colg > qrow_base + r) sA[nt][r] = NEG_BIG;
      }
    }

    float alpha[4];
#pragma unroll
    for (int r = 0; r < 4; ++r) {
      float mx = qmax16(fmaxf(fmaxf(sA[0][r], sA[1][r]), fmaxf(sA[2][r], sA[3][r])));
      float mnew = fmaxf(m[r], mx);
      alpha[r] = exp2f(m[r] - mnew);
      m[r] = mnew;
    }

    float rs[4] = {0.f, 0.f, 0.f, 0.f};
#pragma unroll
    for (int nt = 0; nt < 4; ++nt) {
#pragma unroll
      for (int r = 0; r < 4; ++r) {
        float p = exp2f(sA[nt][r] - m[r]);
        sA[nt][r] = p;
        rs[r] += p;
      }
    }
#pragma unroll
    for (int r = 0; r < 4; ++r) l[r] = l[r] * alpha[r] + qsum16(rs[r]);

    // P: C/D layout -> per-wave LDS -> A layout (same-wave RAW, lgkm-ordered)
#pragma unroll
    for (int nt = 0; nt < 4; ++nt) {
#pragma unroll
      for (int r = 0; r < 4; ++r)
        Ps[w][(quad * 4 + r) * PPITCH + nt * 16 + l15] = (bf16)sA[nt][r];
    }

    // second V half: issue before PV so latency hides under first PV block
    bf16x8 vf1[4];
#pragma unroll
    for (int nt = 0; nt < 4; ++nt) {
      const bf16* vp = base + (size_t)(kt * 4 + 2 + vro) * (size_t)regsz + VOFF +
                       (nt * 16 + l15) * 16 + vco;
      vf1[nt] = ld8(vp);
    }

#pragma unroll
    for (int nt = 0; nt < 4; ++nt) {
#pragma unroll
      for (int r = 0; r < 4; ++r) accO[nt][r] *= alpha[r];
    }
    bf16x8 pf0 = ld8((const bf16*)Ps[w] + l15 * PPITCH + quad * 8);
    bf16x8 pf1 = ld8((const bf16*)Ps[w] + l15 * PPITCH + 32 + quad * 8);
#pragma unroll
    for (int nt = 0; nt < 4; ++nt)
      accO[nt] = __builtin_amdgcn_mfma_f32_16x16x32_bf16(pf0, vf0[nt], accO[nt], 0, 0, 0);
#pragma unroll
    for (int nt = 0; nt < 4; ++nt)
      accO[nt] = __builtin_amdgcn_mfma_f32_16x16x32_bf16(pf1, vf1[nt], accO[nt], 0, 0, 0);
  }

  // merge the 4 kt-quarter partials (exact: O* = sum_w O_w * 2^(m_w - m*))
  if (w > 0) {
#pragma unroll
    for (int nt = 0; nt < 4; ++nt) Mg[w - 1][nt][lane] = accO[nt];
    f32x4 mv = {m[0], m[1], m[2], m[3]};
    f32x4 lv = {l[0], l[1], l[2], l[3]};
    Mg[w - 1][4][lane] = mv;
    Mg[w - 1][5][lane] = lv;
  }
  __syncthreads();
  if (w == 0) {
#pragma unroll
    for (int wv = 0; wv < 3; ++wv) {
      f32x4 mo = Mg[wv][4][lane];
      f32x4 lo = Mg[wv][5][lane];
      f32x4 oo[4];
#pragma unroll
      for (int nt = 0; nt < 4; ++nt) oo[nt] = Mg[wv][nt][lane];
#pragma unroll
      for (int r = 0; r < 4; ++r) {
        float mnew = fmaxf(m[r], mo[r]);
        float a = exp2f(m[r] - mnew);
        float bs = exp2f(mo[r] - mnew);
        l[r] = l[r] * a + lo[r] * bs;
#pragma unroll
        for (int nt = 0; nt < 4; ++nt) accO[nt][r] = accO[nt][r] * a + oo[nt][r] * bs;
        m[r] = mnew;
      }
    }

    float inv[4];
#pragma unroll
    for (int r = 0; r < 4; ++r) inv[r] = 1.f / l[r];
#pragma unroll
    for (int nt = 0; nt < 4; ++nt) {
#pragma unroll
      for (int r = 0; r < 4; ++r) {
        int tk = qt * 64 + slice * 16 + quad * 4 + r;
        int h = nt * 16 + l15;
        out[((size_t)b * T_SZ + tk) * H_SZ + h] = accO[nt][r] * inv[r];
      }
    }
  }
}

// ---------------------------------------------------------------------------
extern "C" void kernel_launch(void* const* d_in, const int* in_sizes, int n_in,
                              void* d_out, int out_size, void* d_ws, size_t ws_size,
                              hipStream_t stream) {
  const float* data = (const float*)d_in[0];

  // Preferred: arena (1024 regions x 4096 bf16 = 8 MB) + Wt (384 KB) in d_ws.
  // Fallback (tiny ws): alias input (stride 32768) + Wt in d_out. Each M=64
  // qkv block fully consumes its own 256 KB input before writing it.
  const size_t arena_bytes = (size_t)1024 * 4096 * sizeof(bf16);  // 8 MB
  const size_t wt_bytes = (size_t)3 * H_SZ * C_SZ * sizeof(bf16); // 384 KB
  bool ws_ok = (d_ws != nullptr) && (ws_size >= arena_bytes + wt_bytes);

  bf16* arena = ws_ok ? (bf16*)d_ws : (bf16*)d_in[0];
  bf16* Wt = ws_ok ? (bf16*)((char*)d_ws + arena_bytes) : (bf16*)d_out;
  int regsz = ws_ok ? 4096 : 32768;

  transpose_w<<<dim3(16, 3), 256, 0, stream>>>((const float*)d_in[1],
                                               (const float*)d_in[2],
                                               (const float*)d_in[3], Wt);
  qkv<<<256, 768, 0, stream>>>(data, Wt, arena, regsz);
  attn<<<1024, 256, 0, stream>>>(arena, (float*)d_out, regsz);
}

// Round 9
// 130.053 us; speedup vs baseline: 1.1847x; 1.1011x over previous
//
#include <hip/hip_runtime.h>
#include <hip/hip_bf16.h>

// B=8, T=2048, C=1024, H=64 single-head causal attention. f32 in, f32 out.
// Round 18: fragment-order pre-packing. R7-R6 natural experiment priced the
// scattered Wt fragment load (16 lines @ 2048B stride) at ~11us/384KB-CU —
// ~10x the L2-BW model; the address PATTERN, not bytes, is the tax. Fix:
// transpose_w now emits Wp in MFMA-fragment order ((j*32+kci)*1024B blocks,
// lane addr l15*64+quad*16) so every qkv wf load is one contiguous 1KB read.
// Same trick for attn's K: qkv epilogue stores K as two contiguous 1024B
// half-fragments (KOFF + half*512 + t*32 + (h&31) elems) so each kf load is
// contiguous. Pure layout permutation; schedule/MFMA structure identical to
// R17 (= R6-equivalent, best at 143.2). fillBufferAligned (2x ~41us, 268 MB
// ws-poison) is unconditional harness overhead — fixed floor.
// Region map: region rt (0..1023) = 16 tokens, stride regsz bf16.
// Q[t][h]@0, K packed@1024 (2 half-frags), V^T[h][t16]@2048.

typedef __bf16 bf16;
typedef __bf16 bf16x8 __attribute__((ext_vector_type(8)));
typedef float f32x4 __attribute__((ext_vector_type(4)));
typedef unsigned int u32;
typedef u32 u32x2 __attribute__((ext_vector_type(2)));
typedef u32 u32x4 __attribute__((ext_vector_type(4)));

#define T_SZ 2048
#define C_SZ 1024
#define H_SZ 64
#define QOFF 0
#define KOFF 1024
#define VOFF 2048
#define PPITCH 72
#define NEG_BIG (-30000.0f)
#define QSCALE 0.04508422f  // (1/32) * log2(e)

__device__ __forceinline__ bf16x8 ld8(const bf16* p) { return *(const bf16x8*)p; }

// DPP rotate within 16-lane row. ROW_ROR:n = 0x120|n.
template <int CTRL>
__device__ __forceinline__ float dpp_mov(float x) {
  return __builtin_bit_cast(float,
      __builtin_amdgcn_update_dpp(0, __builtin_bit_cast(int, x), CTRL, 0xf, 0xf, true));
}
__device__ __forceinline__ float qmax16(float x) {
  x = fmaxf(x, dpp_mov<0x121>(x));
  x = fmaxf(x, dpp_mov<0x122>(x));
  x = fmaxf(x, dpp_mov<0x124>(x));
  x = fmaxf(x, dpp_mov<0x128>(x));
  return x;
}
__device__ __forceinline__ float qsum16(float x) {
  x += dpp_mov<0x121>(x);
  x += dpp_mov<0x122>(x);
  x += dpp_mov<0x124>(x);
  x += dpp_mov<0x128>(x);
  return x;
}

// ---------------------------------------------------------------------------
// Fragment-packed weights: Wp elem[(jj*32+kci)*512 + l15*32 + quad*8 + e] =
// W[c = kci*32+quad*8+e][h = (jj&3)*16+l15] of matrix jj>>2 (0=Q,1=K,2=V).
// QSCALE folded into Wq. Thread (r=h, cb) covers c = ct*64+cb .. +15.
__global__ __launch_bounds__(256) void transpose_w(const float* __restrict__ Wq,
                                                   const float* __restrict__ Wk,
                                                   const float* __restrict__ Wv,
                                                   bf16* __restrict__ Wp) {
  __shared__ float sh[64][65];
  int ct = blockIdx.x;
  int mat = blockIdx.y;
  const float* W = (mat == 0) ? Wq : (mat == 1 ? Wk : Wv);
  int tid = threadIdx.x;
  int r = tid >> 2, cb = (tid & 3) * 16;

  const f32x4* src = (const f32x4*)(W + (size_t)(ct * 64 + r) * H_SZ + cb);
#pragma unroll
  for (int v = 0; v < 4; ++v) {
    f32x4 x = src[v];
#pragma unroll
    for (int jx = 0; jx < 4; ++jx) sh[r][cb + v * 4 + jx] = x[jx];
  }
  __syncthreads();

  float scale = (mat == 0) ? QSCALE : 1.0f;
  bf16x8 o0, o1;
#pragma unroll
  for (int jx = 0; jx < 8; ++jx) o0[jx] = (bf16)(sh[cb + jx][r] * scale);
#pragma unroll
  for (int jx = 0; jx < 8; ++jx) o1[jx] = (bf16)(sh[cb + 8 + jx][r] * scale);

  int jj = mat * 4 + (r >> 4);       // fragment-col 0..11
  int l15 = r & 15;
  int c0 = ct * 64 + cb;
  int kci = c0 >> 5;
  int qa = (c0 >> 3) & 3;            // first quad of the 16-elem span
  bf16* dst = Wp + (size_t)(jj * 32 + kci) * 512 + l15 * 32 + qa * 8;
  *(bf16x8*)dst = o0;        // quad qa   (8 elems)
  *(bf16x8*)(dst + 8) = o1;  // quad qa+1 (8 elems)
}

// ---------------------------------------------------------------------------
// QKV: 256 blocks x 768 thr (12 waves), 1 block/CU, M=64 tokens.
// Wave j (0..11) owns ONE 16-col fragment (j<4 Q, j<8 K, else V) and feeds
// it to 4 MFMAs (row-groups) per kci. Wt traffic 384 KB/CU, and every wf
// load is now a CONTIGUOUS 1KB block (fragment-packed Wp) — 16 sequential
// lines instead of 16 lines @ 2KB stride. LDS: tiled As[kci][row][quad],
// conflict-free 1024B-contiguous df reads.
//   Q/K: mfma(wf, df) -> D[h][t];  V: mfma(df, wf) -> D[t][h].
// K epilogue stores in half-fragment order for attn's contiguous kf loads.
__global__ __launch_bounds__(768, 3) void qkv(const float* data, const bf16* __restrict__ Wp,
                                              bf16* arena, int regsz) {
  __shared__ bf16 As[64 * 1024];  // 128 KiB, tiled addressing via bytes
  char* As_b = (char*)As;
  int blk = blockIdx.x;
  int tid = threadIdx.x;
  int w = tid >> 6, lane = tid & 63;
  int l15 = lane & 15, quad = lane >> 4;

  // ---- stage 64 rows x 1024 f32 -> bf16 LDS (nontemporal, full coverage) --
  const float* src = data + (size_t)blk * 64 * C_SZ;
#pragma unroll
  for (int g = 0; g < 3; ++g) {
    f32x4 st[7];
#pragma unroll
    for (int i = 0; i < 7; ++i) {
      int u = (g * 7 + i) * 768 + tid;  // u < 16128 = rows 0..62
      st[i] = __builtin_nontemporal_load(
          (const f32x4*)(src + (size_t)(u >> 8) * C_SZ + (u & 255) * 4));
    }
#pragma unroll
    for (int i = 0; i < 7; ++i) {
      int u = (g * 7 + i) * 768 + tid;
      int row = u >> 8, c4 = u & 255;
      bf16 t4[4] = {(bf16)st[i][0], (bf16)st[i][1], (bf16)st[i][2], (bf16)st[i][3]};
      int bo = ((c4 >> 3) << 12) + row * 64 + (c4 & 7) * 8;
      *(u32x2*)(As_b + bo) = *(const u32x2*)t4;
    }
  }
  if (tid < 256) {  // tail: row 63
    int c4 = tid;
    f32x4 x = __builtin_nontemporal_load(
        (const f32x4*)(src + (size_t)63 * C_SZ + c4 * 4));
    bf16 t4[4] = {(bf16)x[0], (bf16)x[1], (bf16)x[2], (bf16)x[3]};
    int bo = ((c4 >> 3) << 12) + 63 * 64 + (c4 & 7) * 8;
    *(u32x2*)(As_b + bo) = *(const u32x2*)t4;
  }
  __syncthreads();

  // ---- compute: wave w owns fragment-col j = w ---------------------------
  int j = w;
  const bf16* wb = Wp + (size_t)j * 32 * 512 + l15 * 32 + quad * 8;  // kci stride 512
  bf16x8 wf[2];
  wf[0] = ld8(wb);        // kci 0
  wf[1] = ld8(wb + 512);  // kci 1

  f32x4 acc[4];
  f32x4 zero = {0.f, 0.f, 0.f, 0.f};
#pragma unroll
  for (int rg = 0; rg < 4; ++rg) acc[rg] = zero;

  bool isQK = (j < 8);
  int lbase = l15 * 64 + quad * 16;  // lane offset within a 1024B (kci,rg) slab

#pragma unroll 2
  for (int kci = 0; kci < 32; ++kci) {
    int cur = kci & 1;  // compile-time under unroll 2
    bf16x8 df[4];
#pragma unroll
    for (int rg = 0; rg < 4; ++rg) {
      int bo = (kci << 12) + rg * 1024 + lbase;
      df[rg] = ld8((const bf16*)(As_b + bo));
    }
    if (isQK) {
#pragma unroll
      for (int rg = 0; rg < 4; ++rg)
        acc[rg] = __builtin_amdgcn_mfma_f32_16x16x32_bf16(wf[cur], df[rg], acc[rg], 0, 0, 0);
    } else {
#pragma unroll
      for (int rg = 0; rg < 4; ++rg)
        acc[rg] = __builtin_amdgcn_mfma_f32_16x16x32_bf16(df[rg], wf[cur], acc[rg], 0, 0, 0);
    }
    wf[cur] = ld8(wb + ((kci + 2) & 31) * 512);  // refill for kci+2 (wrap-safe)
  }

  // ---- epilogue: packed 8B stores into 4 sub-regions ---------------------
#pragma unroll
  for (int rg = 0; rg < 4; ++rg) {
    bf16* reg = arena + (size_t)(blk * 4 + rg) * (size_t)regsz;
    bf16 p4[4] = {(bf16)acc[rg][0], (bf16)acc[rg][1], (bf16)acc[rg][2], (bf16)acc[rg][3]};
    if (j < 4) {         // Q: [t][h], t=l15, h = j*16 + quad*4 + r
      bf16* dst = reg + QOFF + l15 * 64 + j * 16 + quad * 4;
      *(u32x2*)dst = *(const u32x2*)p4;
    } else if (j < 8) {  // K: half-fragment order, h = (j-4)*16 + quad*4 + r
      int jk = j - 4;
      bf16* dst = reg + KOFF + (jk >> 1) * 512 + l15 * 32 + (jk & 1) * 16 + quad * 4;
      *(u32x2*)dst = *(const u32x2*)p4;
    } else {             // V: D[t][h] -> V^T[h][t16], h = (j-8)*16 + l15
      bf16* dst = reg + VOFF + ((j - 8) * 16 + l15) * 16 + quad * 4;
      *(u32x2*)dst = *(const u32x2*)p4;
    }
  }
}

// ---------------------------------------------------------------------------
// Flash attention. Block = one (qt, slice, b) 16x64 output tile; 4 waves each
// own a QUARTER of kt in [0, qt], private (m,l,accO); one LDS merge at end.
// Grid 1024 1-D: b = id&7 (pins batch b to XCD b), t = id>>3, slice = t&3,
// qt = 31-(t>>2) (LPT order). 4 blocks/CU -> 16 waves/CU.
// K is stored in half-fragment order: kf loads are contiguous 1KB blocks.
__global__ __launch_bounds__(256, 4) void attn(const bf16* __restrict__ arena,
                                               float* __restrict__ out, int regsz) {
  __shared__ bf16 Ps[4][16 * PPITCH];
  __shared__ f32x4 Mg[3][6][64];  // waves 1..3 dump {accO[0..3], m, l}
  int id = blockIdx.x;
  int b = id & 7;
  int t = id >> 3;
  int slice = t & 3;
  int qt = 31 - (t >> 2);
  int tid = threadIdx.x;
  int w = tid >> 6, lane = tid & 63;
  int l15 = lane & 15, quad = lane >> 4;

  const bf16* base = arena + (size_t)b * 128 * (size_t)regsz;

  const bf16* qreg = base + (size_t)(qt * 4 + slice) * (size_t)regsz + QOFF + l15 * 64;
  bf16x8 qf0 = ld8(qreg + quad * 8);
  bf16x8 qf1 = ld8(qreg + 32 + quad * 8);

  f32x4 accO[4];
  f32x4 zero = {0.f, 0.f, 0.f, 0.f};
#pragma unroll
  for (int nt = 0; nt < 4; ++nt) accO[nt] = zero;
  float m[4], l[4];
#pragma unroll
  for (int r = 0; r < 4; ++r) { m[r] = NEG_BIG; l[r] = 0.f; }

  int qrow_base = qt * 64 + slice * 16 + quad * 4;
  int vro = (quad >> 1);                 // V region sub-index
  int vco = (quad & 1) * 8;              // V in-row offset

  // this wave's kt quarter
  int q4 = (qt + 4) >> 2;                // ceil((qt+1)/4)
  int kbeg = w * q4;
  int kend = min((w + 1) * q4, qt + 1);  // may be empty (kbeg >= kend)

  for (int kt = kbeg; kt < kend; ++kt) {
    // K fragments for this tile (contiguous 1KB half-fragments)
    bf16x8 kf[8];
#pragma unroll
    for (int nt = 0; nt < 4; ++nt) {
      const bf16* kp = base + (size_t)(kt * 4 + nt) * (size_t)regsz + KOFF + l15 * 32 + quad * 8;
      kf[2 * nt] = ld8(kp);          // h 0..31 half
      kf[2 * nt + 1] = ld8(kp + 512);  // h 32..63 half
    }

    f32x4 sA[4];
#pragma unroll
    for (int nt = 0; nt < 4; ++nt) sA[nt] = zero;
#pragma unroll
    for (int nt = 0; nt < 4; ++nt) {
      sA[nt] = __builtin_amdgcn_mfma_f32_16x16x32_bf16(qf0, kf[2 * nt], sA[nt], 0, 0, 0);
      sA[nt] = __builtin_amdgcn_mfma_f32_16x16x32_bf16(qf1, kf[2 * nt + 1], sA[nt], 0, 0, 0);
    }

    // first V half: issue under the softmax (kf regs die at the MFMAs above)
    bf16x8 vf0[4];
#pragma unroll
    for (int nt = 0; nt < 4; ++nt) {
      const bf16* vp = base + (size_t)(kt * 4 + vro) * (size_t)regsz + VOFF +
                       (nt * 16 + l15) * 16 + vco;
      vf0[nt] = ld8(vp);
    }

    if (kt == qt) {  // causal mask on diagonal tile
#pragma unroll
      for (int nt = 0; nt < 4; ++nt) {
        int colg = kt * 64 + nt * 16 + l15;
#pragma unroll
        for (int r = 0; r < 4; ++r)
          if (colg > qrow_base + r) sA[nt][r] = NEG_BIG;
      }
    }

    float alpha[4];
#pragma unroll
    for (int r = 0; r < 4; ++r) {
      float mx = qmax16(fmaxf(fmaxf(sA[0][r], sA[1][r]), fmaxf(sA[2][r], sA[3][r])));
      float mnew = fmaxf(m[r], mx);
      alpha[r] = exp2f(m[r] - mnew);
      m[r] = mnew;
    }

    float rs[4] = {0.f, 0.f, 0.f, 0.f};
#pragma unroll
    for (int nt = 0; nt < 4; ++nt) {
#pragma unroll
      for (int r = 0; r < 4; ++r) {
        float p = exp2f(sA[nt][r] - m[r]);
        sA[nt][r] = p;
        rs[r] += p;
      }
    }
#pragma unroll
    for (int r = 0; r < 4; ++r) l[r] = l[r] * alpha[r] + qsum16(rs[r]);

    // P: C/D layout -> per-wave LDS -> A layout (same-wave RAW, lgkm-ordered)
#pragma unroll
    for (int nt = 0; nt < 4; ++nt) {
#pragma unroll
      for (int r = 0; r < 4; ++r)
        Ps[w][(quad * 4 + r) * PPITCH + nt * 16 + l15] = (bf16)sA[nt][r];
    }

    // second V half: issue before PV so latency hides under first PV block
    bf16x8 vf1[4];
#pragma unroll
    for (int nt = 0; nt < 4; ++nt) {
      const bf16* vp = base + (size_t)(kt * 4 + 2 + vro) * (size_t)regsz + VOFF +
                       (nt * 16 + l15) * 16 + vco;
      vf1[nt] = ld8(vp);
    }

#pragma unroll
    for (int nt = 0; nt < 4; ++nt) {
#pragma unroll
      for (int r = 0; r < 4; ++r) accO[nt][r] *= alpha[r];
    }
    bf16x8 pf0 = ld8((const bf16*)Ps[w] + l15 * PPITCH + quad * 8);
    bf16x8 pf1 = ld8((const bf16*)Ps[w] + l15 * PPITCH + 32 + quad * 8);
#pragma unroll
    for (int nt = 0; nt < 4; ++nt)
      accO[nt] = __builtin_amdgcn_mfma_f32_16x16x32_bf16(pf0, vf0[nt], accO[nt], 0, 0, 0);
#pragma unroll
    for (int nt = 0; nt < 4; ++nt)
      accO[nt] = __builtin_amdgcn_mfma_f32_16x16x32_bf16(pf1, vf1[nt], accO[nt], 0, 0, 0);
  }

  // merge the 4 kt-quarter partials (exact: O* = sum_w O_w * 2^(m_w - m*))
  if (w > 0) {
#pragma unroll
    for (int nt = 0; nt < 4; ++nt) Mg[w - 1][nt][lane] = accO[nt];
    f32x4 mv = {m[0], m[1], m[2], m[3]};
    f32x4 lv = {l[0], l[1], l[2], l[3]};
    Mg[w - 1][4][lane] = mv;
    Mg[w - 1][5][lane] = lv;
  }
  __syncthreads();
  if (w == 0) {
#pragma unroll
    for (int wv = 0; wv < 3; ++wv) {
      f32x4 mo = Mg[wv][4][lane];
      f32x4 lo = Mg[wv][5][lane];
      f32x4 oo[4];
#pragma unroll
      for (int nt = 0; nt < 4; ++nt) oo[nt] = Mg[wv][nt][lane];
#pragma unroll
      for (int r = 0; r < 4; ++r) {
        float mnew = fmaxf(m[r], mo[r]);
        float a = exp2f(m[r] - mnew);
        float bs = exp2f(mo[r] - mnew);
        l[r] = l[r] * a + lo[r] * bs;
#pragma unroll
        for (int nt = 0; nt < 4; ++nt) accO[nt][r] = accO[nt][r] * a + oo[nt][r] * bs;
        m[r] = mnew;
      }
    }

    float inv[4];
#pragma unroll
    for (int r = 0; r < 4; ++r) inv[r] = 1.f / l[r];
#pragma unroll
    for (int nt = 0; nt < 4; ++nt) {
#pragma unroll
      for (int r = 0; r < 4; ++r) {
        int tk = qt * 64 + slice * 16 + quad * 4 + r;
        int h = nt * 16 + l15;
        out[((size_t)b * T_SZ + tk) * H_SZ + h] = accO[nt][r] * inv[r];
      }
    }
  }
}

// ---------------------------------------------------------------------------
extern "C" void kernel_launch(void* const* d_in, const int* in_sizes, int n_in,
                              void* d_out, int out_size, void* d_ws, size_t ws_size,
                              hipStream_t stream) {
  const float* data = (const float*)d_in[0];

  // Preferred: arena (1024 regions x 4096 bf16 = 8 MB) + Wp (384 KB) in d_ws.
  // Fallback (tiny ws): alias input (stride 32768) + Wp in d_out. Each M=64
  // qkv block fully consumes its own 256 KB input before writing it.
  const size_t arena_bytes = (size_t)1024 * 4096 * sizeof(bf16);  // 8 MB
  const size_t wt_bytes = (size_t)3 * H_SZ * C_SZ * sizeof(bf16); // 384 KB
  bool ws_ok = (d_ws != nullptr) && (ws_size >= arena_bytes + wt_bytes);

  bf16* arena = ws_ok ? (bf16*)d_ws : (bf16*)d_in[0];
  bf16* Wp = ws_ok ? (bf16*)((char*)d_ws + arena_bytes) : (bf16*)d_out;
  int regsz = ws_ok ? 4096 : 32768;

  transpose_w<<<dim3(16, 3), 256, 0, stream>>>((const float*)d_in[1],
                                               (const float*)d_in[2],
                                               (const float*)d_in[3], Wp);
  qkv<<<256, 768, 0, stream>>>(data, Wp, arena, regsz);
  attn<<<1024, 256, 0, stream>>>(arena, (float*)d_out, regsz);
}